// Round 5
// baseline (350.146 us; speedup 1.0000x reference)
//
#include <hip/hip_runtime.h>
#include <hip/hip_bf16.h>
#include <stdint.h>

// NodeLevelInnerProductDecoder: out[b,v,:,:] = zeropad(Z_b) @ zeropad(Z_b)^T
// B=64 graphs, D=128, MAX_NODES=508, 4 views. Input fp32, output fp32.
// Write-BW-bound: 264 MB out -> 42 us floor @ 6.3 TB/s. R3 kernel ~127 us at
// 2 blocks/CU (69.6 KB LDS). This rev: 64x64 tiles, 34.8 KB LDS -> 4 blocks/CU,
// 4096 blocks, nontemporal stores (write-once stream, skip L2 allocate).
// R4 fix: nontemporal builtin needs a clang ext_vector, not HIP uint4.

typedef __bf16 v8bf __attribute__((ext_vector_type(8)));
typedef float  v4f  __attribute__((ext_vector_type(4)));
typedef unsigned int v4u __attribute__((ext_vector_type(4)));

#define TILE  64
#define LDA   136    // staging LDS row stride in ushorts (128 data + 8 pad)
#define LDC   68     // epilogue LDS row stride in floats  (64 data + 4 pad)
#define NMAX  508
#define DD    128
#define NV    4

__device__ __forceinline__ unsigned short f32_to_bf16_rne(float f) {
    unsigned int u = __builtin_bit_cast(unsigned int, f);
    u = (u + 0x7fffu + ((u >> 16) & 1u)) >> 16;
    return (unsigned short)u;
}

__global__ __launch_bounds__(256, 4)
void adj_gram_kernel(const float* __restrict__ z,
                     const int*   __restrict__ counts,
                     float*       __restrict__ out)
{
    // 34.8 KB LDS -> 4 blocks/CU (16 waves). Reused as fp32 C-tile (64x68 = 17.4 KB).
    __shared__ __align__(16) unsigned short sAB[2 * TILE * LDA];
    unsigned short* sA = sAB;
    unsigned short* sB = sAB + TILE * LDA;

    const int blk = blockIdx.x;
    const int b   = blk >> 6;          // graph
    const int ti  = (blk >> 3) & 7;    // 8x8 tiles of 64
    const int tj  = blk & 7;
    const int i0  = ti * TILE;
    const int j0  = tj * TILE;

    // node_counts: hedge int32 vs int64 (values 256..508 -> int64 high word is 0)
    const bool is64 = (counts[1] == 0);
    int off = 0;
    for (int g = 0; g < b; ++g) off += is64 ? counts[2 * g] : counts[g];
    const int n = is64 ? counts[2 * b] : counts[b];

    const int tid = threadIdx.x;

    // ---- stage A-tile (rows i0..) and B-tile (rows j0..): fp32 load -> bf16 LDS ----
    {
        const int rs = tid >> 5;        // 0..7  row within pass
        const int cs = tid & 31;        // 4-float (16B) segment of the 128-wide row
        const float* zb = z + (size_t)off * DD;
        #pragma unroll
        for (int p = 0; p < 8; ++p) {
            const int r  = p * 8 + rs;
            const int ga = i0 + r, gb = j0 + r;
            v4f va = (v4f)0.0f, vb = (v4f)0.0f;
            if (ga < n) va = *(const v4f*)(zb + (size_t)ga * DD + cs * 4);
            if (gb < n) vb = *(const v4f*)(zb + (size_t)gb * DD + cs * 4);
            ushort4 pa, pb;
            pa.x = f32_to_bf16_rne(va.x); pa.y = f32_to_bf16_rne(va.y);
            pa.z = f32_to_bf16_rne(va.z); pa.w = f32_to_bf16_rne(va.w);
            pb.x = f32_to_bf16_rne(vb.x); pb.y = f32_to_bf16_rne(vb.y);
            pb.z = f32_to_bf16_rne(vb.z); pb.w = f32_to_bf16_rne(vb.w);
            *(ushort4*)&sA[r * LDA + cs * 4] = pa;   // 8B store, 8B-aligned
            *(ushort4*)&sB[r * LDA + cs * 4] = pb;
        }
    }
    __syncthreads();

    // ---- MFMA: each wave computes a 32x32 quadrant; K = 128 (4 steps of 32) ----
    const int wave = tid >> 6;
    const int lane = tid & 63;
    const int my = (wave >> 1) * 32;
    const int nx = (wave & 1) * 32;
    const int lr = lane & 15;            // A: m-row / B: n-col within 16-tile
    const int lk = (lane >> 4) * 8;      // k sub-offset

    v4f acc[2][2];
    #pragma unroll
    for (int i = 0; i < 2; ++i)
        #pragma unroll
        for (int j = 0; j < 2; ++j) acc[i][j] = (v4f)0.0f;

    #pragma unroll
    for (int ks = 0; ks < 4; ++ks) {
        const int ko = ks * 32 + lk;
        v8bf af[2], bfv[2];
        #pragma unroll
        for (int mt = 0; mt < 2; ++mt)
            af[mt] = *(const v8bf*)&sA[(my + mt * 16 + lr) * LDA + ko];
        #pragma unroll
        for (int nt = 0; nt < 2; ++nt)
            bfv[nt] = *(const v8bf*)&sB[(nx + nt * 16 + lr) * LDA + ko];
        #pragma unroll
        for (int mt = 0; mt < 2; ++mt)
            #pragma unroll
            for (int nt = 0; nt < 2; ++nt)
                acc[mt][nt] = __builtin_amdgcn_mfma_f32_16x16x32_bf16(
                    af[mt], bfv[nt], acc[mt][nt], 0, 0, 0);
    }
    __syncthreads();   // frag reads done; LDS reused as fp32 C-tile

    // ---- repack C (MFMA C layout: col=lane&15, row=(lane>>4)*4+reg) to row-major ----
    float* sC = (float*)sAB;
    const int crow = (lane >> 4) * 4;
    #pragma unroll
    for (int mt = 0; mt < 2; ++mt) {
        #pragma unroll
        for (int nt = 0; nt < 2; ++nt) {
            #pragma unroll
            for (int r = 0; r < 4; ++r) {
                sC[(my + mt * 16 + crow + r) * LDC + (nx + nt * 16 + lr)] =
                    acc[mt][nt][r];
            }
        }
    }
    __syncthreads();

    // ---- write out: 16B nontemporal stores (NMAX%4==0 -> no partial tails), 4 views ----
    const int rs = tid >> 4;     // 0..15 rows per pass
    const int cs = tid & 15;     // 4-float (16B) segment of the 64-wide tile row
    const int gc = j0 + cs * 4;
    #pragma unroll
    for (int p = 0; p < 4; ++p) {
        const int r  = p * 16 + rs;
        const int gr = i0 + r;
        if (gr >= NMAX || gc >= NMAX) continue;    // rows/cols 508..511 of last tiles
        const v4u v = *(const v4u*)&sC[r * LDC + cs * 4];
        const size_t rowbase = (size_t)gr * NMAX + gc;   // multiple of 4 -> 16B aligned
        #pragma unroll
        for (int vv = 0; vv < NV; ++vv) {
            const size_t o = (size_t)(b * NV + vv) * (size_t)(NMAX * NMAX) + rowbase;
            __builtin_nontemporal_store(v, (v4u*)(out + o));
        }
    }
}

extern "C" void kernel_launch(void* const* d_in, const int* in_sizes, int n_in,
                              void* d_out, int out_size, void* d_ws, size_t ws_size,
                              hipStream_t stream) {
    const float* z      = (const float*)d_in[0];
    const int*   counts = (const int*)d_in[1];
    float*       out    = (float*)d_out;
    // 64 graphs x 64 tiles (8x8 of 64^2 over 508 padded nodes)
    adj_gram_kernel<<<dim3(64 * 64), dim3(256), 0, stream>>>(z, counts, out);
}

// Round 6
// 334.470 us; speedup vs baseline: 1.0469x; 1.0469x over previous
//
#include <hip/hip_runtime.h>
#include <hip/hip_bf16.h>
#include <stdint.h>

// NodeLevelInnerProductDecoder: out[b,v,:,:] = zeropad(Z_b) @ zeropad(Z_b)^T
// B=64, D=128, MAX_NODES=508, 4 views. Input fp32, output fp32.
// R6 structure: split unique-compute from view-replication.
//   K1: MFMA gram -> d_ws (66 MB unique, 64x64 tiles, 4 blocks/CU, plain stores)
//   K2: fill-shaped streamer: 1 load + 4 stores per 16B chunk (66 MB rd, 264 MB wr)
// Writes are the roofline: 264+66 MB @ ~6.3 TB/s ~= 55 us + K1 ~15-20 us.

typedef __bf16 v8bf __attribute__((ext_vector_type(8)));
typedef float  v4f  __attribute__((ext_vector_type(4)));
typedef unsigned int v4u __attribute__((ext_vector_type(4)));

#define TILE  64
#define LDA   136    // staging LDS row stride in ushorts (128 data + 8 pad)
#define LDC   68     // epilogue LDS row stride in floats  (64 data + 4 pad)
#define NMAX  508
#define MSZ   (NMAX * NMAX)     // 258064 floats per matrix; *4B = 16B-aligned
#define DD    128
#define NV    4

__device__ __forceinline__ unsigned short f32_to_bf16_rne(float f) {
    unsigned int u = __builtin_bit_cast(unsigned int, f);
    u = (u + 0x7fffu + ((u >> 16) & 1u)) >> 16;
    return (unsigned short)u;
}

// ---------------- Kernel 1: unique gram matrices into workspace ----------------
__global__ __launch_bounds__(256, 4)
void gram_kernel(const float* __restrict__ z,
                 const int*   __restrict__ counts,
                 float*       __restrict__ ws)
{
    __shared__ __align__(16) unsigned short sAB[2 * TILE * LDA];  // 34.8 KB
    unsigned short* sA = sAB;
    unsigned short* sB = sAB + TILE * LDA;

    const int blk = blockIdx.x;
    const int b   = blk >> 6;          // graph
    const int ti  = (blk >> 3) & 7;    // 8x8 tiles of 64
    const int tj  = blk & 7;
    const int i0  = ti * TILE;
    const int j0  = tj * TILE;

    // node_counts: hedge int32 vs int64 (values 256..508 -> int64 high word is 0)
    const bool is64 = (counts[1] == 0);
    int off = 0;
    for (int g = 0; g < b; ++g) off += is64 ? counts[2 * g] : counts[g];
    const int n = is64 ? counts[2 * b] : counts[b];

    const int tid = threadIdx.x;

    // stage A-tile (rows i0..) and B-tile (rows j0..): fp32 load -> bf16 LDS
    {
        const int rs = tid >> 5;        // 0..7
        const int cs = tid & 31;        // 4-float segment of 128-wide row
        const float* zb = z + (size_t)off * DD;
        #pragma unroll
        for (int p = 0; p < 8; ++p) {
            const int r  = p * 8 + rs;
            const int ga = i0 + r, gb = j0 + r;
            v4f va = (v4f)0.0f, vb = (v4f)0.0f;
            if (ga < n) va = *(const v4f*)(zb + (size_t)ga * DD + cs * 4);
            if (gb < n) vb = *(const v4f*)(zb + (size_t)gb * DD + cs * 4);
            ushort4 pa, pb;
            pa.x = f32_to_bf16_rne(va.x); pa.y = f32_to_bf16_rne(va.y);
            pa.z = f32_to_bf16_rne(va.z); pa.w = f32_to_bf16_rne(va.w);
            pb.x = f32_to_bf16_rne(vb.x); pb.y = f32_to_bf16_rne(vb.y);
            pb.z = f32_to_bf16_rne(vb.z); pb.w = f32_to_bf16_rne(vb.w);
            *(ushort4*)&sA[r * LDA + cs * 4] = pa;
            *(ushort4*)&sB[r * LDA + cs * 4] = pb;
        }
    }
    __syncthreads();

    // MFMA: each wave computes a 32x32 quadrant; K = 128
    const int wave = tid >> 6;
    const int lane = tid & 63;
    const int my = (wave >> 1) * 32;
    const int nx = (wave & 1) * 32;
    const int lr = lane & 15;
    const int lk = (lane >> 4) * 8;

    v4f acc[2][2];
    #pragma unroll
    for (int i = 0; i < 2; ++i)
        #pragma unroll
        for (int j = 0; j < 2; ++j) acc[i][j] = (v4f)0.0f;

    #pragma unroll
    for (int ks = 0; ks < 4; ++ks) {
        const int ko = ks * 32 + lk;
        v8bf af[2], bfv[2];
        #pragma unroll
        for (int mt = 0; mt < 2; ++mt)
            af[mt] = *(const v8bf*)&sA[(my + mt * 16 + lr) * LDA + ko];
        #pragma unroll
        for (int nt = 0; nt < 2; ++nt)
            bfv[nt] = *(const v8bf*)&sB[(nx + nt * 16 + lr) * LDA + ko];
        #pragma unroll
        for (int mt = 0; mt < 2; ++mt)
            #pragma unroll
            for (int nt = 0; nt < 2; ++nt)
                acc[mt][nt] = __builtin_amdgcn_mfma_f32_16x16x32_bf16(
                    af[mt], bfv[nt], acc[mt][nt], 0, 0, 0);
    }
    __syncthreads();

    // repack C (MFMA C layout: col=lane&15, row=(lane>>4)*4+reg) to row-major fp32
    float* sC = (float*)sAB;
    const int crow = (lane >> 4) * 4;
    #pragma unroll
    for (int mt = 0; mt < 2; ++mt) {
        #pragma unroll
        for (int nt = 0; nt < 2; ++nt) {
            #pragma unroll
            for (int r = 0; r < 4; ++r) {
                sC[(my + mt * 16 + crow + r) * LDC + (nx + nt * 16 + lr)] =
                    acc[mt][nt][r];
            }
        }
    }
    __syncthreads();

    // write unique gram tile into ws[b][gr][gc]
    const int rs = tid >> 4;     // 0..15
    const int cs = tid & 15;     // 4-float segment of 64-wide tile row
    const int gc = j0 + cs * 4;
    float* wb = ws + (size_t)b * MSZ;
    #pragma unroll
    for (int p = 0; p < 4; ++p) {
        const int r  = p * 16 + rs;
        const int gr = i0 + r;
        if (gr >= NMAX || gc >= NMAX) continue;
        const v4u v = *(const v4u*)&sC[r * LDC + cs * 4];
        *(v4u*)(wb + (size_t)gr * NMAX + gc) = v;   // 16B aligned (508%4==0)
    }
}

// ---------------- Kernel 2: replicate ws -> out across 4 views ----------------
// One 16B chunk per thread: 1 load + 4 plain stores (fill-kernel shape).
#define CHUNKS (MSZ / 4)   // 64516 16B-chunks per matrix

__global__ __launch_bounds__(256)
void replicate_kernel(const float* __restrict__ ws, float* __restrict__ out)
{
    const int b = blockIdx.y;                         // graph
    const int c = blockIdx.x * 256 + threadIdx.x;     // chunk within matrix
    if (c >= CHUNKS) return;
    const size_t e = (size_t)c * 4;
    const v4u v = *(const v4u*)(ws + (size_t)b * MSZ + e);
    float* o = out + (size_t)b * NV * MSZ + e;
    *(v4u*)(o)           = v;
    *(v4u*)(o + MSZ)     = v;
    *(v4u*)(o + 2 * MSZ) = v;
    *(v4u*)(o + 3 * MSZ) = v;
}

extern "C" void kernel_launch(void* const* d_in, const int* in_sizes, int n_in,
                              void* d_out, int out_size, void* d_ws, size_t ws_size,
                              hipStream_t stream) {
    const float* z      = (const float*)d_in[0];
    const int*   counts = (const int*)d_in[1];
    float*       out    = (float*)d_out;
    float*       ws     = (float*)d_ws;   // needs 66.06 MB; poison fill shows ~1 GiB avail

    gram_kernel<<<dim3(64 * 64), dim3(256), 0, stream>>>(z, counts, ws);
    // 253 blocks x 256 = 64768 threads >= 64516 chunks; y = 64 graphs
    replicate_kernel<<<dim3((CHUNKS + 255) / 256, 64), dim3(256), 0, stream>>>(ws, out);
}